// Round 3
// baseline (1846.057 us; speedup 1.0000x reference)
//
#include <hip/hip_runtime.h>
#include <stdint.h>

#define Bsz 4
#define Lsz 512
#define Dsz 768
#define Wsz 12
#define LWsz (Lsz * Wsz)        /* 6144  */
#define Nh   (Bsz * Lsz * Dsz)  /* 1572864: h elems       */
#define Npw  (2 * Dsz * Dsz)    /* 1179648: proj_w elems  */
#define Npb  (2 * Dsz)          /* 1536 */
#define Now  (Dsz * 3 * Dsz)    /* 1769472: out_w elems   */
#define Nob  (Dsz)              /* 768 */
#define Nbt2 (Dsz * Wsz * Dsz)  /* 7077888 */
#define Nsp  (Bsz * Lsz * Wsz * 2) /* 49152 span entries */
#define Nrp  (Bsz * Lsz * 2 * Dsz) /* 3145728 rproj */
#define Nrc  (Bsz * Lsz * Wsz * Dsz) /* 18874368 rconv */
#define LDSS 68                 /* f32 stride of [k][m] LDS tiles */

typedef __attribute__((ext_vector_type(4))) float f32x4;
typedef unsigned short u16;
typedef unsigned int u32;

static __device__ __forceinline__ float bf2f(u16 u) {
    union { u32 i; float f; } c; c.i = ((u32)u) << 16; return c.f;
}
static __device__ __forceinline__ u16 f2bf(float f) {
    union { float f; u32 i; } c; c.f = f;
    u32 u = c.i + 0x7FFFu + ((c.i >> 16) & 1u);
    return (u16)(u >> 16);
}

// ---------- dtype detection (deterministic; same result every call) ----------
// flags[0] = 1 if float tensors are f32 (else bf16); flags[1] = 1 if span is i64.
__global__ void detect_k(const u32* __restrict__ hw, const u32* __restrict__ sw,
                         int* __restrict__ flags) {
    __shared__ int cnt[2];
    if (threadIdx.x == 0) { cnt[0] = 0; cnt[1] = 0; }
    __syncthreads();
    int c0 = 0;
    for (int i = threadIdx.x; i < 2048; i += 256) {
        u32 e = (hw[i] >> 23) & 0xFFu;           // f32 exponent field
        if (e >= 118u && e <= 130u) c0++;        // |x| in ~[2^-9, 8]: true for N(0,1) f32
    }
    int c1 = 0;
    for (int i = threadIdx.x; i < 512; i += 256)
        if (sw[2 * i + 1] == 0u) c1++;           // i64 high words of values in [0,512) are 0
    atomicAdd(&cnt[0], c0);
    atomicAdd(&cnt[1], c1);
    __syncthreads();
    if (threadIdx.x == 0) {
        flags[0] = (cnt[0] > 1024) ? 1 : 0;
        flags[1] = (cnt[1] >= 512) ? 1 : 0;
    }
}

// ---------- canonicalize a float tensor to bf16 ----------
__global__ void pack_bf16(const void* __restrict__ src, u16* __restrict__ dst,
                          int n, const int* __restrict__ flags) {
    int i = blockIdx.x * 256 + threadIdx.x;
    if (i >= n) return;
    dst[i] = flags[0] ? f2bf(((const float*)src)[i]) : ((const u16*)src)[i];
}

// ---------- conv_w (o,c,j) -> bt2[o][j*768 + c], canonical bf16 ----------
__global__ void pack_conv(const void* __restrict__ src, u16* __restrict__ dst,
                          const int* __restrict__ flags) {
    int idx = blockIdx.x * 256 + threadIdx.x;
    if (idx >= Nbt2) return;
    int c = idx % Dsz;
    int t = idx / Dsz;
    int j = t % Wsz;
    int o = t / Wsz;
    size_t s = (size_t)(o * Dsz + c) * Wsz + j;
    dst[idx] = flags[0] ? f2bf(((const float*)src)[s]) : ((const u16*)src)[s];
}

// ---------- span -> canonical clipped int32 ----------
__global__ void pack_span(const int* __restrict__ sp, int* __restrict__ dst,
                          const int* __restrict__ flags) {
    int i = blockIdx.x * 256 + threadIdx.x;
    if (i >= Nsp) return;
    int v = flags[1] ? sp[2 * i] : sp[i];        // i64: little-endian low word
    v = v < 0 ? 0 : (v > Lsz - 1 ? Lsz - 1 : v);
    dst[i] = v;
}

// ---------- shared VALU GEMM pieces ----------
// LDS tiles are [k=0..31][m=0..63] f32, stride LDSS. Stage from bf16 row-major
// src rows (row, K) with 8-elem vector loads.
static __device__ __forceinline__ void stage_tile(float* lds, const u16* src) {
    // src points at element (row sm, col 0) region already offset by caller:
    // caller passes src = base + row*K + ktile, we add sk here.
    // (this helper is specialized inline at call sites instead)
}

#define GEMM_PROLOG()                                                     \
    __shared__ float ldsA[32 * LDSS];                                     \
    __shared__ float ldsB[32 * LDSS];                                     \
    const int tid = threadIdx.x;                                          \
    const int tx = tid & 15;       /* n-dir, 4 cols each */               \
    const int ty = tid >> 4;       /* m-dir, 4 rows each */               \
    const int sm = tid >> 2;       /* staging row 0..63  */               \
    const int sk = (tid & 3) * 8;  /* staging col 0,8,16,24 */            \
    float acc[4][4] = {{0.f, 0.f, 0.f, 0.f}, {0.f, 0.f, 0.f, 0.f},        \
                       {0.f, 0.f, 0.f, 0.f}, {0.f, 0.f, 0.f, 0.f}};

#define STAGE8(ldst, vec)                                                 \
    do {                                                                  \
        uint4 _t = (vec);                                                 \
        const u16* _p = (const u16*)&_t;                                  \
        _Pragma("unroll")                                                 \
        for (int _i = 0; _i < 8; ++_i)                                    \
            (ldst)[(sk + _i) * LDSS + sm] = bf2f(_p[_i]);                 \
    } while (0)

#define INNER32()                                                         \
    _Pragma("unroll")                                                     \
    for (int kk = 0; kk < 32; ++kk) {                                     \
        f32x4 av = *(const f32x4*)&ldsA[kk * LDSS + ty * 4];              \
        f32x4 bv = *(const f32x4*)&ldsB[kk * LDSS + tx * 4];              \
        _Pragma("unroll")                                                 \
        for (int _i = 0; _i < 4; ++_i)                                    \
            _Pragma("unroll")                                             \
            for (int _j = 0; _j < 4; ++_j)                                \
                acc[_i][_j] += av[_i] * bv[_j];                           \
    }

// ---------- GEMM 1: rproj = relu(h @ proj_w^T + proj_b) ----------
// M=2048 N=1536 K=768
__global__ __launch_bounds__(256) void vgemm_proj(const u16* __restrict__ A,
                                                  const u16* __restrict__ Bt,
                                                  const u16* __restrict__ bias,
                                                  u16* __restrict__ C) {
    GEMM_PROLOG();
    const int bm = blockIdx.x * 64, bn = blockIdx.y * 64;
    for (int kt = 0; kt < 768; kt += 32) {
        uint4 ta = *(const uint4*)(A + (size_t)(bm + sm) * 768 + kt + sk);
        uint4 tb = *(const uint4*)(Bt + (size_t)(bn + sm) * 768 + kt + sk);
        STAGE8(ldsA, ta);
        STAGE8(ldsB, tb);
        __syncthreads();
        INNER32();
        __syncthreads();
    }
    float bv[4];
#pragma unroll
    for (int j = 0; j < 4; ++j) bv[j] = bf2f(bias[bn + tx * 4 + j]);
#pragma unroll
    for (int i = 0; i < 4; ++i) {
        int row = bm + ty * 4 + i;
        ushort4 st;
        u16* sp = (u16*)&st;
#pragma unroll
        for (int j = 0; j < 4; ++j) {
            float v = acc[i][j] + bv[j];
            sp[j] = f2bf(v > 0.f ? v : 0.f);
        }
        *(ushort4*)&C[(size_t)row * 1536 + bn + tx * 4] = st;
    }
}

// ---------- GEMM 2: conv prefix GEMM with per-j relu snapshots ----------
// M=2048 rows (b,l); A[m, j*768+c] = (l+j<512) ? h[b,l+j,c] : 0;  N=768
__global__ __launch_bounds__(256) void vgemm_conv(const u16* __restrict__ H,
                                                  const u16* __restrict__ Bt2,
                                                  u16* __restrict__ Cv) {
    GEMM_PROLOG();
    const int bm = blockIdx.x * 64, bn = blockIdx.y * 64;
    const int row = bm + sm;
    const int l = row & (Lsz - 1);
    for (int j = 0; j < Wsz; ++j) {
        for (int kt = 0; kt < 768; kt += 32) {
            uint4 ta = {0u, 0u, 0u, 0u};
            if (l + j < Lsz)
                ta = *(const uint4*)(H + (size_t)(row + j) * 768 + kt + sk);
            uint4 tb = *(const uint4*)(Bt2 + (size_t)(bn + sm) * (Wsz * 768) + j * 768 + kt + sk);
            STAGE8(ldsA, ta);
            STAGE8(ldsB, tb);
            __syncthreads();
            INNER32();
            __syncthreads();
        }
        // snapshot: rconv[(m*12 + j)*768 + col] = relu(acc)
#pragma unroll
        for (int i = 0; i < 4; ++i) {
            int m = bm + ty * 4 + i;
            ushort4 st;
            u16* sp = (u16*)&st;
#pragma unroll
            for (int jj = 0; jj < 4; ++jj) {
                float v = acc[i][jj];
                sp[jj] = f2bf(v > 0.f ? v : 0.f);
            }
            *(ushort4*)&Cv[((size_t)m * Wsz + j) * 768 + bn + tx * 4] = st;
        }
    }
}

// ---------- GEMM 3: out = relu(relu(cat) @ out_w^T + out_b) ----------
// M=24576 gathered rows; K=2304 (3 segments); N=768. Output dtype per flags[0].
__global__ __launch_bounds__(256) void vgemm_out(const u16* __restrict__ RP,
                                                 const u16* __restrict__ RC,
                                                 const int* __restrict__ SPn,
                                                 const u16* __restrict__ Bt,
                                                 const u16* __restrict__ bias,
                                                 void* __restrict__ out,
                                                 const int* __restrict__ flags) {
    GEMM_PROLOG();
    __shared__ u32 offs[3][64];
    const int bm = blockIdx.x * 64, bn = blockIdx.y * 64;
    if (tid < 64) {
        int n = bm + tid;
        int b = n / LWsz;
        int s0 = SPn[2 * n], s1 = SPn[2 * n + 1];
        offs[0][tid] = (u32)((b * Lsz + s0) * 1536);
        offs[1][tid] = (u32)((b * Lsz + s1) * 1536 + 768);
        offs[2][tid] = (u32)(n * 768);
    }
    __syncthreads();
    for (int seg = 0; seg < 3; ++seg) {
        const u16* src = (seg == 2) ? RC : RP;
        for (int kt = 0; kt < 768; kt += 32) {
            uint4 ta = *(const uint4*)(src + (size_t)offs[seg][sm] + kt + sk);
            uint4 tb = *(const uint4*)(Bt + (size_t)(bn + sm) * 2304 + seg * 768 + kt + sk);
            STAGE8(ldsA, ta);
            STAGE8(ldsB, tb);
            __syncthreads();
            INNER32();
            __syncthreads();
        }
    }
    const int isf32 = flags[0];
    float bv[4];
#pragma unroll
    for (int j = 0; j < 4; ++j) bv[j] = bf2f(bias[bn + tx * 4 + j]);
#pragma unroll
    for (int i = 0; i < 4; ++i) {
        int row = bm + ty * 4 + i;
        float v[4];
#pragma unroll
        for (int j = 0; j < 4; ++j) {
            float t = acc[i][j] + bv[j];
            v[j] = t > 0.f ? t : 0.f;
        }
        if (isf32) {
            f32x4 st = {v[0], v[1], v[2], v[3]};
            *(f32x4*)&((float*)out)[(size_t)row * 768 + bn + tx * 4] = st;
        } else {
            ushort4 st;
            u16* sp = (u16*)&st;
#pragma unroll
            for (int j = 0; j < 4; ++j) sp[j] = f2bf(v[j]);
            *(ushort4*)&((u16*)out)[(size_t)row * 768 + bn + tx * 4] = st;
        }
    }
}

extern "C" void kernel_launch(void* const* d_in, const int* in_sizes, int n_in,
                              void* d_out, int out_size, void* d_ws, size_t ws_size,
                              hipStream_t stream) {
    const void* h      = d_in[0];
    const void* span   = d_in[1];
    const void* proj_w = d_in[2];
    const void* proj_b = d_in[3];
    const void* conv_w = d_in[4];
    const void* out_w  = d_in[5];
    const void* out_b  = d_in[6];

    // ---- workspace layout (bytes; all chunks 16B-aligned) ----
    char* p = (char*)d_ws;
    int* flags = (int*)p;                 p += 64;
    u16* ch    = (u16*)p;                 p += (size_t)Nh   * 2;
    u16* cpw   = (u16*)p;                 p += (size_t)Npw  * 2;
    u16* cpb   = (u16*)p;                 p += (size_t)Npb  * 2;
    u16* cow   = (u16*)p;                 p += (size_t)Now  * 2;
    u16* cob   = (u16*)p;                 p += (size_t)Nob  * 2;
    u16* bt2   = (u16*)p;                 p += (size_t)Nbt2 * 2;
    u16* rproj = (u16*)p;                 p += (size_t)Nrp  * 2;
    u16* rconv = (u16*)p;                 p += (size_t)Nrc  * 2;
    int* cspan = (int*)p;                 /* + Nsp*4 ; total ~64.5 MB */

    detect_k<<<1, 256, 0, stream>>>((const u32*)h, (const u32*)span, flags);

    pack_bf16<<<(Nh  + 255) / 256, 256, 0, stream>>>(h,      ch,  Nh,  flags);
    pack_bf16<<<(Npw + 255) / 256, 256, 0, stream>>>(proj_w, cpw, Npw, flags);
    pack_bf16<<<(Npb + 255) / 256, 256, 0, stream>>>(proj_b, cpb, Npb, flags);
    pack_bf16<<<(Now + 255) / 256, 256, 0, stream>>>(out_w,  cow, Now, flags);
    pack_bf16<<<(Nob + 255) / 256, 256, 0, stream>>>(out_b,  cob, Nob, flags);
    pack_conv<<<(Nbt2 + 255) / 256, 256, 0, stream>>>(conv_w, bt2, flags);
    pack_span<<<(Nsp + 255) / 256, 256, 0, stream>>>((const int*)span, cspan, flags);

    vgemm_proj<<<dim3(32, 24), 256, 0, stream>>>(ch, cpw, cpb, rproj);
    vgemm_conv<<<dim3(32, 12), 256, 0, stream>>>(ch, bt2, rconv);
    vgemm_out<<<dim3(384, 12), 256, 0, stream>>>(rproj, rconv, cspan, cow, cob,
                                                 d_out, flags);
}

// Round 4
// 494.720 us; speedup vs baseline: 3.7315x; 3.7315x over previous
//
#include <hip/hip_runtime.h>
#include <stdint.h>

#define Bsz 4
#define Lsz 512
#define Dsz 768
#define Wsz 12
#define LWsz (Lsz * Wsz)        /* 6144  */
#define Nh   (Bsz * Lsz * Dsz)  /* 1572864 */
#define Npw  (2 * Dsz * Dsz)    /* 1179648 */
#define Npb  (2 * Dsz)          /* 1536 */
#define Now  (Dsz * 3 * Dsz)    /* 1769472 */
#define Nob  (Dsz)              /* 768 */
#define Nbt2 (Dsz * Wsz * Dsz)  /* 7077888 */
#define Nsp  (Bsz * Lsz * Wsz * 2) /* 49152 */
#define Nrp  (Bsz * Lsz * 2 * Dsz) /* 3145728 */
#define Nrc  (Bsz * Lsz * Wsz * Dsz) /* 18874368 */
#define Kconv (Wsz * Dsz)       /* 9216 */

typedef __attribute__((ext_vector_type(8))) __bf16 bf16x8;
typedef __attribute__((ext_vector_type(4))) float f32x4;
typedef unsigned short u16;
typedef unsigned int u32;

// MFMA guarded so the module builds on ANY compilation target (theory: R0/R1
// .so builds failed because the gfx950-gated builtin hard-errors on a
// non-gfx950 pass). On gfx950 __has_builtin is true -> real MFMA.
#if __has_builtin(__builtin_amdgcn_mfma_f32_16x16x32_bf16)
#define HAVE_MFMA950 1
#else
#define HAVE_MFMA950 0
#endif

static __device__ __forceinline__ f32x4 mfma_bf16(bf16x8 a, bf16x8 b, f32x4 c) {
#if HAVE_MFMA950
    return __builtin_amdgcn_mfma_f32_16x16x32_bf16(a, b, c, 0, 0, 0);
#else
    return c;  // never executed on MI355X
#endif
}

static __device__ __forceinline__ float bf2f(u16 u) {
    union { u32 i; float f; } c; c.i = ((u32)u) << 16; return c.f;
}
static __device__ __forceinline__ u16 f2bf(float f) {
    union { float f; u32 i; } c; c.f = f;
    u32 u = c.i + 0x7FFFu + ((c.i >> 16) & 1u);
    return (u16)(u >> 16);
}

// ---------- dtype detection (unchanged from passing R3) ----------
__global__ void detect_k(const u32* __restrict__ hw, const u32* __restrict__ sw,
                         int* __restrict__ flags) {
    __shared__ int cnt[2];
    if (threadIdx.x == 0) { cnt[0] = 0; cnt[1] = 0; }
    __syncthreads();
    int c0 = 0;
    for (int i = threadIdx.x; i < 2048; i += 256) {
        u32 e = (hw[i] >> 23) & 0xFFu;
        if (e >= 118u && e <= 130u) c0++;
    }
    int c1 = 0;
    for (int i = threadIdx.x; i < 512; i += 256)
        if (sw[2 * i + 1] == 0u) c1++;
    atomicAdd(&cnt[0], c0);
    atomicAdd(&cnt[1], c1);
    __syncthreads();
    if (threadIdx.x == 0) {
        flags[0] = (cnt[0] > 1024) ? 1 : 0;
        flags[1] = (cnt[1] >= 512) ? 1 : 0;
    }
}

__global__ void pack_bf16(const void* __restrict__ src, u16* __restrict__ dst,
                          int n, const int* __restrict__ flags) {
    int i = blockIdx.x * 256 + threadIdx.x;
    if (i >= n) return;
    dst[i] = flags[0] ? f2bf(((const float*)src)[i]) : ((const u16*)src)[i];
}

__global__ void pack_conv(const void* __restrict__ src, u16* __restrict__ dst,
                          const int* __restrict__ flags) {
    int idx = blockIdx.x * 256 + threadIdx.x;
    if (idx >= Nbt2) return;
    int c = idx % Dsz;
    int t = idx / Dsz;
    int j = t % Wsz;
    int o = t / Wsz;
    size_t s = (size_t)(o * Dsz + c) * Wsz + j;
    dst[idx] = flags[0] ? f2bf(((const float*)src)[s]) : ((const u16*)src)[s];
}

__global__ void pack_span(const int* __restrict__ sp, int* __restrict__ dst,
                          const int* __restrict__ flags) {
    int i = blockIdx.x * 256 + threadIdx.x;
    if (i >= Nsp) return;
    int v = flags[1] ? sp[2 * i] : sp[i];
    v = v < 0 ? 0 : (v > Lsz - 1 ? Lsz - 1 : v);
    dst[i] = v;
}

// ================= MFMA GEMM kernels (128x128 tile, 4 waves, 4x4 frags) =====
// LDS tiles [row][k] u16, stride 40 (max 2-way bank aliasing = free).
// Frag layouts per m89/m91: A[m=lane&15][k=(lane>>4)*8+j]; C/D col=lane&15,
// row=(lane>>4)*4+reg.

#define MF_PROLOG()                                                       \
    __shared__ __align__(16) u16 lds_a[128 * 40];                         \
    __shared__ __align__(16) u16 lds_b[128 * 40];                         \
    const int tid = threadIdx.x;                                          \
    const int lane = tid & 63;                                            \
    const int wave = tid >> 6;                                            \
    const int wm = wave & 1, wn = wave >> 1;                              \
    const int lcol = lane & 15;                                           \
    const int quad = lane >> 4;                                           \
    const int sr = tid >> 2;                                              \
    const int sc = (tid & 3) * 8;                                         \
    f32x4 acc[4][4] = {};

#define MF_COMPUTE()                                                      \
    do {                                                                  \
        __syncthreads();                                                  \
        bf16x8 af[4], bfr[4];                                             \
        _Pragma("unroll")                                                 \
        for (int _i = 0; _i < 4; ++_i)                                    \
            af[_i] = *(const bf16x8*)&lds_a[(wm * 64 + _i * 16 + lcol) * 40 + quad * 8]; \
        _Pragma("unroll")                                                 \
        for (int _j = 0; _j < 4; ++_j)                                    \
            bfr[_j] = *(const bf16x8*)&lds_b[(wn * 64 + _j * 16 + lcol) * 40 + quad * 8]; \
        _Pragma("unroll")                                                 \
        for (int _i = 0; _i < 4; ++_i)                                    \
            _Pragma("unroll")                                             \
            for (int _j = 0; _j < 4; ++_j)                                \
                acc[_i][_j] = mfma_bf16(af[_i], bfr[_j], acc[_i][_j]);    \
        __syncthreads();                                                  \
    } while (0)

// ---------- GEMM 1: rproj = relu(h @ proj_w^T + proj_b);  M2048 N1536 K768 --
__global__ __launch_bounds__(256) void mgemm_proj(const u16* __restrict__ A,
                                                  const u16* __restrict__ Bt,
                                                  const u16* __restrict__ bias,
                                                  u16* __restrict__ C) {
    MF_PROLOG();
    const int bm = blockIdx.x * 128, bn = blockIdx.y * 128;
    const u16* a0 = A + (size_t)(bm + sr) * 768 + sc;
    const u16* b0 = Bt + (size_t)(bn + sr) * 768 + sc;
    for (int kb = 0; kb < 768; kb += 32) {
        *(uint4*)&lds_a[sr * 40 + sc]        = *(const uint4*)(a0 + kb);
        *(uint4*)&lds_a[(sr + 64) * 40 + sc] = *(const uint4*)(a0 + (size_t)64 * 768 + kb);
        *(uint4*)&lds_b[sr * 40 + sc]        = *(const uint4*)(b0 + kb);
        *(uint4*)&lds_b[(sr + 64) * 40 + sc] = *(const uint4*)(b0 + (size_t)64 * 768 + kb);
        MF_COMPUTE();
    }
#pragma unroll
    for (int i = 0; i < 4; ++i)
#pragma unroll
        for (int j = 0; j < 4; ++j) {
            int col = bn + wn * 64 + j * 16 + lcol;
            float bv = bf2f(bias[col]);
#pragma unroll
            for (int r = 0; r < 4; ++r) {
                int row = bm + wm * 64 + i * 16 + quad * 4 + r;
                float v = acc[i][j][r] + bv;
                C[(size_t)row * 1536 + col] = f2bf(v > 0.f ? v : 0.f);
            }
        }
}

// ---------- GEMM 2: conv prefix GEMM with per-j relu snapshots --------------
// M2048 N768; A[m, j*768+c] = (l+j<512) ? h[b,l+j,c] : 0
__global__ __launch_bounds__(256) void mgemm_conv(const u16* __restrict__ H,
                                                  const u16* __restrict__ Bt2,
                                                  u16* __restrict__ Cv) {
    MF_PROLOG();
    const int bm = blockIdx.x * 128, bn = blockIdx.y * 128;
    const int row0 = bm + sr, row1 = row0 + 64;
    const int l0 = row0 & (Lsz - 1), l1 = row1 & (Lsz - 1);
    const u16* a0 = H + (size_t)row0 * 768 + sc;
    const u16* a1 = H + (size_t)row1 * 768 + sc;
    const u16* b0 = Bt2 + (size_t)(bn + sr) * Kconv + sc;
    const uint4 zero = {0u, 0u, 0u, 0u};
    for (int j = 0; j < Wsz; ++j) {
        for (int kb = 0; kb < 768; kb += 32) {
            uint4 ta0 = (l0 + j < Lsz) ? *(const uint4*)(a0 + (size_t)j * 768 + kb) : zero;
            uint4 ta1 = (l1 + j < Lsz) ? *(const uint4*)(a1 + (size_t)j * 768 + kb) : zero;
            *(uint4*)&lds_a[sr * 40 + sc]        = ta0;
            *(uint4*)&lds_a[(sr + 64) * 40 + sc] = ta1;
            *(uint4*)&lds_b[sr * 40 + sc]        = *(const uint4*)(b0 + j * 768 + kb);
            *(uint4*)&lds_b[(sr + 64) * 40 + sc] = *(const uint4*)(b0 + (size_t)64 * Kconv + j * 768 + kb);
            MF_COMPUTE();
        }
#pragma unroll
        for (int i = 0; i < 4; ++i)
#pragma unroll
            for (int jj = 0; jj < 4; ++jj) {
                int col = bn + wn * 64 + jj * 16 + lcol;
#pragma unroll
                for (int r = 0; r < 4; ++r) {
                    int row = bm + wm * 64 + i * 16 + quad * 4 + r;
                    float v = acc[i][jj][r];
                    Cv[((size_t)row * Wsz + j) * 768 + col] = f2bf(v > 0.f ? v : 0.f);
                }
            }
    }
}

// ---------- GEMM 3: out = relu(relu(cat) @ out_w^T + out_b) -----------------
// M24576 (gathered) N768 K2304; runtime f32/bf16 output.
__global__ __launch_bounds__(256) void mgemm_out(const u16* __restrict__ RP,
                                                 const u16* __restrict__ RC,
                                                 const int* __restrict__ SPn,
                                                 const u16* __restrict__ Bt,
                                                 const u16* __restrict__ bias,
                                                 void* __restrict__ out,
                                                 const int* __restrict__ flags) {
    MF_PROLOG();
    __shared__ u32 offs[3][128];
    const int bm = blockIdx.x * 128, bn = blockIdx.y * 128;
    if (tid < 128) {
        int n = bm + tid;
        int b = n / LWsz;
        int s0 = SPn[2 * n], s1 = SPn[2 * n + 1];
        offs[0][tid] = (u32)((b * Lsz + s0) * 1536);
        offs[1][tid] = (u32)((b * Lsz + s1) * 1536 + 768);
        offs[2][tid] = (u32)(n * 768);
    }
    __syncthreads();
    const u16* b0 = Bt + (size_t)(bn + sr) * 2304 + sc;
#pragma unroll 1
    for (int seg = 0; seg < 3; ++seg) {
        const u16* src = (seg == 2) ? RC : RP;
        const u32 o0 = offs[seg][sr], o1 = offs[seg][sr + 64];
        for (int kb = 0; kb < 768; kb += 32) {
            *(uint4*)&lds_a[sr * 40 + sc]        = *(const uint4*)(src + (size_t)o0 + kb + sc);
            *(uint4*)&lds_a[(sr + 64) * 40 + sc] = *(const uint4*)(src + (size_t)o1 + kb + sc);
            *(uint4*)&lds_b[sr * 40 + sc]        = *(const uint4*)(b0 + seg * 768 + kb);
            *(uint4*)&lds_b[(sr + 64) * 40 + sc] = *(const uint4*)(b0 + (size_t)64 * 2304 + seg * 768 + kb);
            MF_COMPUTE();
        }
    }
    const int isf32 = flags[0];
#pragma unroll
    for (int i = 0; i < 4; ++i)
#pragma unroll
        for (int j = 0; j < 4; ++j) {
            int col = bn + wn * 64 + j * 16 + lcol;
            float bv = bf2f(bias[col]);
#pragma unroll
            for (int r = 0; r < 4; ++r) {
                int row = bm + wm * 64 + i * 16 + quad * 4 + r;
                float v = acc[i][j][r] + bv;
                v = v > 0.f ? v : 0.f;
                if (isf32) ((float*)out)[(size_t)row * 768 + col] = v;
                else       ((u16*)out)[(size_t)row * 768 + col] = f2bf(v);
            }
        }
}

extern "C" void kernel_launch(void* const* d_in, const int* in_sizes, int n_in,
                              void* d_out, int out_size, void* d_ws, size_t ws_size,
                              hipStream_t stream) {
    const void* h      = d_in[0];
    const void* span   = d_in[1];
    const void* proj_w = d_in[2];
    const void* proj_b = d_in[3];
    const void* conv_w = d_in[4];
    const void* out_w  = d_in[5];
    const void* out_b  = d_in[6];

    char* p = (char*)d_ws;
    int* flags = (int*)p;                 p += 64;
    u16* ch    = (u16*)p;                 p += (size_t)Nh   * 2;
    u16* cpw   = (u16*)p;                 p += (size_t)Npw  * 2;
    u16* cpb   = (u16*)p;                 p += (size_t)Npb  * 2;
    u16* cow   = (u16*)p;                 p += (size_t)Now  * 2;
    u16* cob   = (u16*)p;                 p += (size_t)Nob  * 2;
    u16* bt2   = (u16*)p;                 p += (size_t)Nbt2 * 2;
    u16* rproj = (u16*)p;                 p += (size_t)Nrp  * 2;
    u16* rconv = (u16*)p;                 p += (size_t)Nrc  * 2;
    int* cspan = (int*)p;

    detect_k<<<1, 256, 0, stream>>>((const u32*)h, (const u32*)span, flags);

    pack_bf16<<<(Nh  + 255) / 256, 256, 0, stream>>>(h,      ch,  Nh,  flags);
    pack_bf16<<<(Npw + 255) / 256, 256, 0, stream>>>(proj_w, cpw, Npw, flags);
    pack_bf16<<<(Npb + 255) / 256, 256, 0, stream>>>(proj_b, cpb, Npb, flags);
    pack_bf16<<<(Now + 255) / 256, 256, 0, stream>>>(out_w,  cow, Now, flags);
    pack_bf16<<<(Nob + 255) / 256, 256, 0, stream>>>(out_b,  cob, Nob, flags);
    pack_conv<<<(Nbt2 + 255) / 256, 256, 0, stream>>>(conv_w, bt2, flags);
    pack_span<<<(Nsp + 255) / 256, 256, 0, stream>>>((const int*)span, cspan, flags);

    mgemm_proj<<<dim3(16, 12), 256, 0, stream>>>(ch, cpw, cpb, rproj);
    mgemm_conv<<<dim3(16, 6), 256, 0, stream>>>(ch, bt2, rconv);
    mgemm_out<<<dim3(192, 6), 256, 0, stream>>>(rproj, rconv, cspan, cow, cob,
                                                d_out, flags);
}

// Round 5
// 368.724 us; speedup vs baseline: 5.0066x; 1.3417x over previous
//
#include <hip/hip_runtime.h>
#include <stdint.h>

#define Bsz 4
#define Lsz 512
#define Dsz 768
#define Wsz 12
#define LWsz (Lsz * Wsz)        /* 6144  */
#define Nh   (Bsz * Lsz * Dsz)  /* 1572864 */
#define Npw  (2 * Dsz * Dsz)    /* 1179648 */
#define Npb  (2 * Dsz)          /* 1536 */
#define Now  (Dsz * 3 * Dsz)    /* 1769472 */
#define Nob  (Dsz)              /* 768 */
#define Nbt2 (Dsz * Wsz * Dsz)  /* 7077888 */
#define Nsp  (Bsz * Lsz * Wsz * 2) /* 49152 */
#define Nrp  (Bsz * Lsz * 2 * Dsz) /* 3145728 */
#define Nrc  (Bsz * Lsz * Wsz * Dsz) /* 18874368 */
#define Kconv (Wsz * Dsz)       /* 9216 */

typedef __attribute__((ext_vector_type(8))) __bf16 bf16x8;
typedef __attribute__((ext_vector_type(4))) float f32x4;
typedef unsigned short u16;
typedef unsigned int u32;

#if __has_builtin(__builtin_amdgcn_mfma_f32_16x16x32_bf16)
#define HAVE_MFMA950 1
#else
#define HAVE_MFMA950 0
#endif

static __device__ __forceinline__ f32x4 mfma_bf16(bf16x8 a, bf16x8 b, f32x4 c) {
#if HAVE_MFMA950
    return __builtin_amdgcn_mfma_f32_16x16x32_bf16(a, b, c, 0, 0, 0);
#else
    return c;  // never executed on MI355X
#endif
}

static __device__ __forceinline__ float bf2f(u16 u) {
    union { u32 i; float f; } c; c.i = ((u32)u) << 16; return c.f;
}
static __device__ __forceinline__ u16 f2bf(float f) {
    union { float f; u32 i; } c; c.f = f;
    u32 u = c.i + 0x7FFFu + ((c.i >> 16) & 1u);
    return (u16)(u >> 16);
}

// ---------- dtype detection (unchanged, verified R3/R4) ----------
__global__ void detect_k(const u32* __restrict__ hw, const u32* __restrict__ sw,
                         int* __restrict__ flags) {
    __shared__ int cnt[2];
    if (threadIdx.x == 0) { cnt[0] = 0; cnt[1] = 0; }
    __syncthreads();
    int c0 = 0;
    for (int i = threadIdx.x; i < 2048; i += 256) {
        u32 e = (hw[i] >> 23) & 0xFFu;
        if (e >= 118u && e <= 130u) c0++;
    }
    int c1 = 0;
    for (int i = threadIdx.x; i < 512; i += 256)
        if (sw[2 * i + 1] == 0u) c1++;
    atomicAdd(&cnt[0], c0);
    atomicAdd(&cnt[1], c1);
    __syncthreads();
    if (threadIdx.x == 0) {
        flags[0] = (cnt[0] > 1024) ? 1 : 0;
        flags[1] = (cnt[1] >= 512) ? 1 : 0;
    }
}

__global__ void pack_bf16(const void* __restrict__ src, u16* __restrict__ dst,
                          int n, const int* __restrict__ flags) {
    int i = blockIdx.x * 256 + threadIdx.x;
    if (i >= n) return;
    dst[i] = flags[0] ? f2bf(((const float*)src)[i]) : ((const u16*)src)[i];
}

__global__ void pack_conv(const void* __restrict__ src, u16* __restrict__ dst,
                          const int* __restrict__ flags) {
    int idx = blockIdx.x * 256 + threadIdx.x;
    if (idx >= Nbt2) return;
    int c = idx % Dsz;
    int t = idx / Dsz;
    int j = t % Wsz;
    int o = t / Wsz;
    size_t s = (size_t)(o * Dsz + c) * Wsz + j;
    dst[idx] = flags[0] ? f2bf(((const float*)src)[s]) : ((const u16*)src)[s];
}

__global__ void pack_span(const int* __restrict__ sp, int* __restrict__ dst,
                          const int* __restrict__ flags) {
    int i = blockIdx.x * 256 + threadIdx.x;
    if (i >= Nsp) return;
    int v = flags[1] ? sp[2 * i] : sp[i];
    v = v < 0 ? 0 : (v > Lsz - 1 ? Lsz - 1 : v);
    dst[i] = v;
}

// ================= MFMA GEMM kernels (128x128 tile, 4 waves, 4x4 frags) =====
#define MF_PROLOG()                                                       \
    __shared__ __align__(16) u16 lds_a[128 * 40];                         \
    __shared__ __align__(16) u16 lds_b[128 * 40];                         \
    const int tid = threadIdx.x;                                          \
    const int lane = tid & 63;                                            \
    const int wave = tid >> 6;                                            \
    const int wm = wave & 1, wn = wave >> 1;                              \
    const int lcol = lane & 15;                                           \
    const int quad = lane >> 4;                                           \
    const int sr = tid >> 2;                                              \
    const int sc = (tid & 3) * 8;                                         \
    f32x4 acc[4][4] = {};

#define MF_COMPUTE()                                                      \
    do {                                                                  \
        __syncthreads();                                                  \
        bf16x8 af[4], bfr[4];                                             \
        _Pragma("unroll")                                                 \
        for (int _i = 0; _i < 4; ++_i)                                    \
            af[_i] = *(const bf16x8*)&lds_a[(wm * 64 + _i * 16 + lcol) * 40 + quad * 8]; \
        _Pragma("unroll")                                                 \
        for (int _j = 0; _j < 4; ++_j)                                    \
            bfr[_j] = *(const bf16x8*)&lds_b[(wn * 64 + _j * 16 + lcol) * 40 + quad * 8]; \
        _Pragma("unroll")                                                 \
        for (int _i = 0; _i < 4; ++_i)                                    \
            _Pragma("unroll")                                             \
            for (int _j = 0; _j < 4; ++_j)                                \
                acc[_i][_j] = mfma_bf16(af[_i], bfr[_j], acc[_i][_j]);    \
        __syncthreads();                                                  \
    } while (0)

// ---------- GEMM 1: rproj = relu(h @ proj_w^T + proj_b);  M2048 N1536 K768 --
__global__ __launch_bounds__(256) void mgemm_proj(const u16* __restrict__ A,
                                                  const u16* __restrict__ Bt,
                                                  const u16* __restrict__ bias,
                                                  u16* __restrict__ C) {
    MF_PROLOG();
    const int bm = blockIdx.x * 128, bn = blockIdx.y * 128;
    const u16* a0 = A + (size_t)(bm + sr) * 768 + sc;
    const u16* b0 = Bt + (size_t)(bn + sr) * 768 + sc;
    for (int kb = 0; kb < 768; kb += 32) {
        *(uint4*)&lds_a[sr * 40 + sc]        = *(const uint4*)(a0 + kb);
        *(uint4*)&lds_a[(sr + 64) * 40 + sc] = *(const uint4*)(a0 + (size_t)64 * 768 + kb);
        *(uint4*)&lds_b[sr * 40 + sc]        = *(const uint4*)(b0 + kb);
        *(uint4*)&lds_b[(sr + 64) * 40 + sc] = *(const uint4*)(b0 + (size_t)64 * 768 + kb);
        MF_COMPUTE();
    }
#pragma unroll
    for (int i = 0; i < 4; ++i)
#pragma unroll
        for (int j = 0; j < 4; ++j) {
            int col = bn + wn * 64 + j * 16 + lcol;
            float bv = bf2f(bias[col]);
#pragma unroll
            for (int r = 0; r < 4; ++r) {
                int row = bm + wm * 64 + i * 16 + quad * 4 + r;
                float v = acc[i][j][r] + bv;
                C[(size_t)row * 1536 + col] = f2bf(v > 0.f ? v : 0.f);
            }
        }
}

// ---------- GEMM 2a: independent per-j conv contributions ------------------
// grid (16, 6, 12): contrib_j[m, col] = shift_j(h) @ conv_w_j^T, stored RAW
// (no relu) bf16 into Cv[(m*12 + j)*768 + col]. 1152 blocks vs 96 before.
__global__ __launch_bounds__(256) void mgemm_convc(const u16* __restrict__ H,
                                                   const u16* __restrict__ Bt2,
                                                   u16* __restrict__ Cv) {
    MF_PROLOG();
    const int j = blockIdx.z;
    const int bm = blockIdx.x * 128, bn = blockIdx.y * 128;
    const int row0 = bm + sr, row1 = row0 + 64;
    const int l0 = row0 & (Lsz - 1), l1 = row1 & (Lsz - 1);
    const u16* a0 = H + (size_t)(row0 + j) * 768 + sc;
    const u16* a1 = H + (size_t)(row1 + j) * 768 + sc;
    const u16* b0 = Bt2 + (size_t)(bn + sr) * Kconv + (size_t)j * 768 + sc;
    const uint4 zero = {0u, 0u, 0u, 0u};
    const bool v0 = (l0 + j < Lsz), v1 = (l1 + j < Lsz);
    for (int kb = 0; kb < 768; kb += 32) {
        *(uint4*)&lds_a[sr * 40 + sc]        = v0 ? *(const uint4*)(a0 + kb) : zero;
        *(uint4*)&lds_a[(sr + 64) * 40 + sc] = v1 ? *(const uint4*)(a1 + kb) : zero;
        *(uint4*)&lds_b[sr * 40 + sc]        = *(const uint4*)(b0 + kb);
        *(uint4*)&lds_b[(sr + 64) * 40 + sc] = *(const uint4*)(b0 + (size_t)64 * Kconv + kb);
        MF_COMPUTE();
    }
#pragma unroll
    for (int i = 0; i < 4; ++i)
#pragma unroll
        for (int jj = 0; jj < 4; ++jj) {
            int col = bn + wn * 64 + jj * 16 + lcol;
#pragma unroll
            for (int r = 0; r < 4; ++r) {
                int row = bm + wm * 64 + i * 16 + quad * 4 + r;
                Cv[((size_t)row * Wsz + j) * 768 + col] = f2bf(acc[i][jj][r]);
            }
        }
}

// ---------- GEMM 2b: in-place running sum over j + relu --------------------
// Each thread owns one row m and 8 cols across all 12 j's -> no races.
__global__ __launch_bounds__(256) void cumsum_relu(u16* __restrict__ Cv) {
    int idx = blockIdx.x * 256 + threadIdx.x;
    const int total = (Bsz * Lsz) * (Dsz / 8);   /* 2048 * 96 */
    if (idx >= total) return;
    int m = idx / (Dsz / 8);
    int c = (idx % (Dsz / 8)) * 8;
    u16* p = Cv + (size_t)m * Wsz * 768 + c;
    float s[8] = {0.f, 0.f, 0.f, 0.f, 0.f, 0.f, 0.f, 0.f};
#pragma unroll
    for (int j = 0; j < Wsz; ++j) {
        uint4 t = *(const uint4*)(p + (size_t)j * 768);
        const u16* q = (const u16*)&t;
        uint4 o;
        u16* qo = (u16*)&o;
#pragma unroll
        for (int i = 0; i < 8; ++i) {
            s[i] += bf2f(q[i]);
            qo[i] = f2bf(s[i] > 0.f ? s[i] : 0.f);
        }
        *(uint4*)(p + (size_t)j * 768) = o;
    }
}

// ---------- GEMM 3: out = relu(relu(cat) @ out_w^T + out_b) -----------------
__global__ __launch_bounds__(256) void mgemm_out(const u16* __restrict__ RP,
                                                 const u16* __restrict__ RC,
                                                 const int* __restrict__ SPn,
                                                 const u16* __restrict__ Bt,
                                                 const u16* __restrict__ bias,
                                                 void* __restrict__ out,
                                                 const int* __restrict__ flags) {
    MF_PROLOG();
    __shared__ u32 offs[3][128];
    const int bm = blockIdx.x * 128, bn = blockIdx.y * 128;
    if (tid < 128) {
        int n = bm + tid;
        int b = n / LWsz;
        int s0 = SPn[2 * n], s1 = SPn[2 * n + 1];
        offs[0][tid] = (u32)((b * Lsz + s0) * 1536);
        offs[1][tid] = (u32)((b * Lsz + s1) * 1536 + 768);
        offs[2][tid] = (u32)(n * 768);
    }
    __syncthreads();
    const u16* b0 = Bt + (size_t)(bn + sr) * 2304 + sc;
#pragma unroll 1
    for (int seg = 0; seg < 3; ++seg) {
        const u16* src = (seg == 2) ? RC : RP;
        const u32 o0 = offs[seg][sr], o1 = offs[seg][sr + 64];
        for (int kb = 0; kb < 768; kb += 32) {
            *(uint4*)&lds_a[sr * 40 + sc]        = *(const uint4*)(src + (size_t)o0 + kb + sc);
            *(uint4*)&lds_a[(sr + 64) * 40 + sc] = *(const uint4*)(src + (size_t)o1 + kb + sc);
            *(uint4*)&lds_b[sr * 40 + sc]        = *(const uint4*)(b0 + seg * 768 + kb);
            *(uint4*)&lds_b[(sr + 64) * 40 + sc] = *(const uint4*)(b0 + (size_t)64 * 2304 + seg * 768 + kb);
            MF_COMPUTE();
        }
    }
    const int isf32 = flags[0];
#pragma unroll
    for (int i = 0; i < 4; ++i)
#pragma unroll
        for (int j = 0; j < 4; ++j) {
            int col = bn + wn * 64 + j * 16 + lcol;
            float bv = bf2f(bias[col]);
#pragma unroll
            for (int r = 0; r < 4; ++r) {
                int row = bm + wm * 64 + i * 16 + quad * 4 + r;
                float v = acc[i][j][r] + bv;
                v = v > 0.f ? v : 0.f;
                if (isf32) ((float*)out)[(size_t)row * 768 + col] = v;
                else       ((u16*)out)[(size_t)row * 768 + col] = f2bf(v);
            }
        }
}

extern "C" void kernel_launch(void* const* d_in, const int* in_sizes, int n_in,
                              void* d_out, int out_size, void* d_ws, size_t ws_size,
                              hipStream_t stream) {
    const void* h      = d_in[0];
    const void* span   = d_in[1];
    const void* proj_w = d_in[2];
    const void* proj_b = d_in[3];
    const void* conv_w = d_in[4];
    const void* out_w  = d_in[5];
    const void* out_b  = d_in[6];

    char* p = (char*)d_ws;
    int* flags = (int*)p;                 p += 64;
    u16* ch    = (u16*)p;                 p += (size_t)Nh   * 2;
    u16* cpw   = (u16*)p;                 p += (size_t)Npw  * 2;
    u16* cpb   = (u16*)p;                 p += (size_t)Npb  * 2;
    u16* cow   = (u16*)p;                 p += (size_t)Now  * 2;
    u16* cob   = (u16*)p;                 p += (size_t)Nob  * 2;
    u16* bt2   = (u16*)p;                 p += (size_t)Nbt2 * 2;
    u16* rproj = (u16*)p;                 p += (size_t)Nrp  * 2;
    u16* rconv = (u16*)p;                 p += (size_t)Nrc  * 2;
    int* cspan = (int*)p;

    detect_k<<<1, 256, 0, stream>>>((const u32*)h, (const u32*)span, flags);

    pack_bf16<<<(Nh  + 255) / 256, 256, 0, stream>>>(h,      ch,  Nh,  flags);
    pack_bf16<<<(Npw + 255) / 256, 256, 0, stream>>>(proj_w, cpw, Npw, flags);
    pack_bf16<<<(Npb + 255) / 256, 256, 0, stream>>>(proj_b, cpb, Npb, flags);
    pack_bf16<<<(Now + 255) / 256, 256, 0, stream>>>(out_w,  cow, Now, flags);
    pack_bf16<<<(Nob + 255) / 256, 256, 0, stream>>>(out_b,  cob, Nob, flags);
    pack_conv<<<(Nbt2 + 255) / 256, 256, 0, stream>>>(conv_w, bt2, flags);
    pack_span<<<(Nsp + 255) / 256, 256, 0, stream>>>((const int*)span, cspan, flags);

    mgemm_proj<<<dim3(16, 12), 256, 0, stream>>>(ch, cpw, cpb, rproj);
    mgemm_convc<<<dim3(16, 6, 12), 256, 0, stream>>>(ch, bt2, rconv);
    cumsum_relu<<<((Bsz * Lsz) * (Dsz / 8) + 255) / 256, 256, 0, stream>>>(rconv);
    mgemm_out<<<dim3(192, 6), 256, 0, stream>>>(rproj, rconv, cspan, cow, cob,
                                                d_out, flags);
}